// Round 7
// baseline (750.012 us; speedup 1.0000x reference)
//
#include <hip/hip_runtime.h>
#include <hip/hip_bf16.h>

// GCNConv, gather formulation. History:
//  R1: scatter f32 atomics (400MB EA write-through)        566us
//  R3: CSR gather (random-atomic fill)                     500us
//  R5: bf16 h + MFMA gemm                                  398us  (fill 135us)
//  R6: bucket counting-sort CSR                            247us  (gather 95.6us)
//  R7: packed u32 pairs, NPB=64, finalize+gather fused into per-bucket
//      LDS f32-atomic accumulate (deletes sorted_row/offsets/finalize).
constexpr int N_NODES = 100000;
constexpr int IN_F    = 128;
constexpr int OUT_F   = 64;
constexpr int N_EDGES = 1600000;

constexpr int NPB    = 64;                        // nodes per bucket (col>>6)
constexpr int NB     = (N_NODES + NPB - 1) / NPB; // 1563 buckets
constexpr int B_SORT = 256;                       // hist/scatter blocks
constexpr int EPB    = N_EDGES / B_SORT;          // 6250 edges per block

typedef short bf16x8 __attribute__((ext_vector_type(8)));
typedef float f32x4  __attribute__((ext_vector_type(4)));

static __device__ __forceinline__ unsigned short f2b(float f) {
    __hip_bfloat16 h = __float2bfloat16(f);
    return *reinterpret_cast<unsigned short*>(&h);
}
static __device__ __forceinline__ float blo(unsigned int u) {
    return __uint_as_float(u << 16);
}
static __device__ __forceinline__ float bhi(unsigned int u) {
    return __uint_as_float(u & 0xffff0000u);
}

// --------------------------------------------- K1: per-block bucket histogram
__global__ __launch_bounds__(256) void hist_kernel(const int* __restrict__ col,
                                                   int* __restrict__ hist_g) {
    __shared__ int hist[NB];
    for (int i = threadIdx.x; i < NB; i += 256) hist[i] = 0;
    __syncthreads();
    const int beg = blockIdx.x * EPB;
    for (int e = beg + threadIdx.x; e < beg + EPB; e += 256)
        atomicAdd(&hist[col[e] >> 6], 1);
    __syncthreads();
    for (int i = threadIdx.x; i < NB; i += 256)
        hist_g[i * B_SORT + blockIdx.x] = hist[i];
}

// ------------------- K2a: per-bucket scan over blocks (in-place) + bin totals
__global__ __launch_bounds__(256) void scanbins_kernel(int* __restrict__ hist_g,
                                                       int* __restrict__ binTotal) {
    __shared__ int s[B_SORT];
    const int bin = blockIdx.x, t = threadIdx.x;
    int v = hist_g[bin * B_SORT + t];
    s[t] = v;
    __syncthreads();
#pragma unroll
    for (int off = 1; off < B_SORT; off <<= 1) {
        int u = (t >= off) ? s[t - off] : 0;
        __syncthreads();
        s[t] += u;
        __syncthreads();
    }
    hist_g[bin * B_SORT + t] = s[t] - v;          // exclusive within bin
    if (t == B_SORT - 1) binTotal[bin] = s[t];
}

// --------------------- K2b: scan bucket totals -> bucket starts (2/thread)
__global__ __launch_bounds__(1024) void scanoff_kernel(const int* __restrict__ binTotal,
                                                       int* __restrict__ binStart) {
    __shared__ int s[1024];
    const int t = threadIdx.x;
    const int i0 = 2 * t, i1 = 2 * t + 1;
    int v0 = (i0 < NB) ? binTotal[i0] : 0;
    int v1 = (i1 < NB) ? binTotal[i1] : 0;
    s[t] = v0 + v1;
    __syncthreads();
#pragma unroll
    for (int off = 1; off < 1024; off <<= 1) {
        int u = (t >= off) ? s[t - off] : 0;
        __syncthreads();
        s[t] += u;
        __syncthreads();
    }
    int base = s[t] - v0 - v1;                    // exclusive at i0
    if (i0 < NB) binStart[i0] = base;
    if (i1 < NB) binStart[i1] = base + v0;
    if (t == 0) binStart[NB] = N_EDGES;
}

// ---------- K3: bucket-partition packed edges (LDS cursors, no g-atomics)
__global__ __launch_bounds__(256) void scatter_kernel(const int* __restrict__ eidx,
                                                      const int* __restrict__ hist_g,
                                                      const int* __restrict__ binStart,
                                                      unsigned int* __restrict__ packs) {
    __shared__ int cur[NB];
    for (int i = threadIdx.x; i < NB; i += 256)
        cur[i] = binStart[i] + hist_g[i * B_SORT + blockIdx.x];
    __syncthreads();
    const int beg = blockIdx.x * EPB;
    for (int e = beg + threadIdx.x; e < beg + EPB; e += 256) {
        int row = eidx[e];
        int col = eidx[N_EDGES + e];
        int p = atomicAdd(&cur[col >> 6], 1);     // LDS atomic only
        packs[p] = ((unsigned)row << 6) | (unsigned)(col & 63);
    }
}

// ----------------------------- K4: per-bucket degree -> dis = rsqrt(deg+1)
__global__ __launch_bounds__(256) void degdis_kernel(const unsigned int* __restrict__ packs,
                                                     const int* __restrict__ binStart,
                                                     float* __restrict__ dis) {
    __shared__ int cnt[NPB];
    const int b = blockIdx.x, t = threadIdx.x;
    if (t < NPB) cnt[t] = 0;
    __syncthreads();
    const int beg = binStart[b], end = binStart[b + 1];
    for (int i = beg + t; i < end; i += 256)
        atomicAdd(&cnt[packs[i] & 63], 1);
    __syncthreads();
    const int n0 = b << 6;
    if (t < NPB && n0 + t < N_NODES)
        dis[n0 + t] = rsqrtf((float)cnt[t] + 1.0f);
}

// ------------------------------------------------- W [128][64] -> WT bf16 --
__global__ __launch_bounds__(256) void wt_kernel(const float* __restrict__ W,
                                                 unsigned short* __restrict__ WT) {
    int idx = blockIdx.x * 256 + threadIdx.x;
    if (idx < IN_F * OUT_F) {
        int k = idx >> 6, n = idx & 63;
        WT[n * IN_F + k] = f2b(W[idx]);
    }
}

// --------------------------------------------------- h = bf16(x @ W) -------
// mfma_f32_16x16x32_bf16; LDS XOR-swizzled bf16 tiles (verified R5/R6).
constexpr int GEMM_ROWS = 64;
__global__ __launch_bounds__(256) void gemm_kernel(const float* __restrict__ x,
                                                   const unsigned short* __restrict__ WT,
                                                   unsigned short* __restrict__ h) {
    __shared__ unsigned short Xs[GEMM_ROWS][IN_F];   // 16 KB
    __shared__ unsigned short Ws[OUT_F][IN_F];       // 16 KB (W^T: [n][k])
    const int tid = threadIdx.x;
    const int row0 = blockIdx.x * GEMM_ROWS;

#pragma unroll
    for (int j = 0; j < 4; ++j) {
        int g  = tid + j * 256;
        int n  = g >> 4;
        int k8 = (g & 15) * 8;
        bf16x8 v = *(const bf16x8*)&WT[n * IN_F + k8];
        *(bf16x8*)&Ws[n][k8 ^ ((n & 7) << 3)] = v;
    }
    {
        int r    = tid >> 2;
        int grow = row0 + r;
        if (grow >= N_NODES) grow = N_NODES - 1;
        int ks   = (tid & 3) * 32;
        const float4* xp = (const float4*)x + (long)grow * (IN_F / 4) + (ks >> 2);
        int sw = (r & 7) << 3;
#pragma unroll
        for (int j = 0; j < 8; ++j) {
            float4 xv = xp[j];
            unsigned int u0 = (unsigned int)f2b(xv.x) | ((unsigned int)f2b(xv.y) << 16);
            unsigned int u1 = (unsigned int)f2b(xv.z) | ((unsigned int)f2b(xv.w) << 16);
            uint2 pr; pr.x = u0; pr.y = u1;
            *(uint2*)&Xs[r][(ks + j * 4) ^ sw] = pr;
        }
    }
    __syncthreads();

    const int w    = tid >> 6;
    const int lane = tid & 63;
    const int ml   = lane & 15;
    const int kg   = lane >> 4;

    const int rowA = w * 16 + ml;
    const int swA  = (rowA & 7) << 3;

    bf16x8 a[4];
#pragma unroll
    for (int kt = 0; kt < 4; ++kt)
        a[kt] = *(const bf16x8*)&Xs[rowA][(kt * 32 + kg * 8) ^ swA];

    f32x4 acc[4];
#pragma unroll
    for (int ct = 0; ct < 4; ++ct) acc[ct] = (f32x4)(0.0f);

#pragma unroll
    for (int ct = 0; ct < 4; ++ct) {
        int n  = ct * 16 + ml;
        int sw = (n & 7) << 3;
#pragma unroll
        for (int kt = 0; kt < 4; ++kt) {
            bf16x8 bv = *(const bf16x8*)&Ws[n][(kt * 32 + kg * 8) ^ sw];
            acc[ct] = __builtin_amdgcn_mfma_f32_16x16x32_bf16(a[kt], bv, acc[ct], 0, 0, 0);
        }
    }

    const int grow0 = row0 + w * 16 + kg * 4;
#pragma unroll
    for (int ct = 0; ct < 4; ++ct) {
#pragma unroll
        for (int i = 0; i < 4; ++i) {
            int r = grow0 + i;
            if (r < N_NODES)
                h[(long)r * OUT_F + ct * 16 + ml] = f2b(acc[ct][i]);
        }
    }
}

// --------------- K5: fused gather: per-bucket LDS f32 accumulate + epilogue
// One block per bucket. 8 edge-streams (4 waves x 2 halves); half-wave lane
// sl covers the full 128B bf16 h row of its edge's source. Messages land in
// acc[64][65] (pad: halves collide at worst 4-way). out written once.
__global__ __launch_bounds__(256) void gather_kernel(const unsigned int* __restrict__ packs,
                                                     const int* __restrict__ binStart,
                                                     const float* __restrict__ dis,
                                                     const unsigned int* __restrict__ h2,
                                                     const float* __restrict__ bias,
                                                     float* __restrict__ out) {
    __shared__ float acc[NPB][OUT_F + 1];   // 16.6 KB
    __shared__ float disL[NPB];
    const int b = blockIdx.x, t = threadIdx.x;
    const int n0 = b << 6;

    for (int i = t; i < NPB * (OUT_F + 1); i += 256) ((float*)acc)[i] = 0.0f;
    if (t < NPB) disL[t] = (n0 + t < N_NODES) ? dis[n0 + t] : 0.0f;
    __syncthreads();

    const int lane   = t & 63;
    const int sl     = lane & 31;
    const int stream = ((t >> 6) << 1) | (lane >> 5);   // 0..7
    const int beg = binStart[b], end = binStart[b + 1];

    for (int i = beg + stream; i < end; i += 8) {
        unsigned int pk = packs[i];                     // uniform per half
        int row = pk >> 6;
        int c   = pk & 63;
        float wn = dis[row] * disL[c];
        unsigned int u = h2[row * 32 + sl];             // 128B coalesced
        atomicAdd(&acc[c][2 * sl], wn * blo(u));
        atomicAdd(&acc[c][2 * sl + 1], wn * bhi(u));
    }
    __syncthreads();

    const int w = t >> 6;
    for (int c = w; c < NPB; c += 4) {
        int node = n0 + c;
        if (node >= N_NODES) break;                     // uniform per wave
        unsigned int us = h2[node * 32 + (lane >> 1)];
        float selfv = (lane & 1) ? bhi(us) : blo(us);
        float dcc = disL[c];
        out[node * 64 + lane] = acc[c][lane] + bias[lane] + dcc * dcc * selfv;
    }
}

// ---------------------------------------------------------------------------
extern "C" void kernel_launch(void* const* d_in, const int* in_sizes, int n_in,
                              void* d_out, int out_size, void* d_ws, size_t ws_size,
                              hipStream_t stream) {
    const float* x   = (const float*)d_in[0];
    const int*   idx = (const int*)d_in[1];   // [2, E], delivered as int32
    const float* W   = (const float*)d_in[2];
    const float* b   = (const float*)d_in[3];
    float*       out = (float*)d_out;

    int* p = (int*)d_ws;
    unsigned int* packs = (unsigned int*)p;  p += N_EDGES;       // 6.4 MB
    int* hist_g   = p;                       p += NB * B_SORT;   // 1.6 MB
    int* binTotal = p;                       p += NB + 4;
    int* binStart = p;                       p += NB + 4;
    float* dis    = (float*)p;               p += N_NODES;
    p = (int*)(((uintptr_t)p + 15) & ~(uintptr_t)15);            // 16B align
    unsigned short* WT = (unsigned short*)p; p += IN_F * OUT_F / 2;
    unsigned short* hb = (unsigned short*)p;                     // 12.8 MB

    hist_kernel<<<B_SORT, 256, 0, stream>>>(idx + N_EDGES, hist_g);
    scanbins_kernel<<<NB, B_SORT, 0, stream>>>(hist_g, binTotal);
    scanoff_kernel<<<1, 1024, 0, stream>>>(binTotal, binStart);
    scatter_kernel<<<B_SORT, 256, 0, stream>>>(idx, hist_g, binStart, packs);
    wt_kernel<<<(IN_F * OUT_F + 255) / 256, 256, 0, stream>>>(W, WT);
    gemm_kernel<<<(N_NODES + GEMM_ROWS - 1) / GEMM_ROWS, 256, 0, stream>>>(x, WT, hb);
    degdis_kernel<<<NB, 256, 0, stream>>>(packs, binStart, dis);
    gather_kernel<<<NB, 256, 0, stream>>>(packs, binStart, dis,
                                          (const unsigned int*)hb, b, out);
}

// Round 8
// 214.998 us; speedup vs baseline: 3.4885x; 3.4885x over previous
//
#include <hip/hip_runtime.h>
#include <hip/hip_bf16.h>

// GCNConv, gather formulation. History:
//  R1: scatter f32 atomics (400MB EA write-through)        566us
//  R3: CSR gather (random-atomic fill)                     500us
//  R5: bf16 h + MFMA gemm                                  398us  (fill 135us)
//  R6: bucket counting-sort CSR, register-accum gather     247us  (gather 95.6us)
//  R7: LDS-f32-atomic fused gather — REGRESSION 750us (ds_add serialization)
//  R8: revert to register-accum gather; packed u32 edges; CSR build fused
//      into gather (LDS-local sort); h pre-scaled by dis at gemm.
constexpr int N_NODES = 100000;
constexpr int IN_F    = 128;
constexpr int OUT_F   = 64;
constexpr int N_EDGES = 1600000;

constexpr int NPB    = 64;                        // nodes per bucket (col>>6)
constexpr int NB     = (N_NODES + NPB - 1) / NPB; // 1563 buckets
constexpr int B_SORT = 256;                       // hist/scatter blocks
constexpr int EPB    = N_EDGES / B_SORT;          // 6250 edges per block
constexpr int STAGE_CAP = 1600;                   // bucket stage (mean 1024, +18 sigma)

typedef short bf16x8 __attribute__((ext_vector_type(8)));
typedef float f32x4  __attribute__((ext_vector_type(4)));

static __device__ __forceinline__ unsigned short f2b(float f) {
    __hip_bfloat16 h = __float2bfloat16(f);
    return *reinterpret_cast<unsigned short*>(&h);
}
static __device__ __forceinline__ float blo(unsigned int u) {
    return __uint_as_float(u << 16);
}
static __device__ __forceinline__ float bhi(unsigned int u) {
    return __uint_as_float(u & 0xffff0000u);
}

// --------------------------------------------- K1: per-block bucket histogram
__global__ __launch_bounds__(256) void hist_kernel(const int* __restrict__ col,
                                                   int* __restrict__ hist_g) {
    __shared__ int hist[NB];
    for (int i = threadIdx.x; i < NB; i += 256) hist[i] = 0;
    __syncthreads();
    const int beg = blockIdx.x * EPB;
    for (int e = beg + threadIdx.x; e < beg + EPB; e += 256)
        atomicAdd(&hist[col[e] >> 6], 1);
    __syncthreads();
    for (int i = threadIdx.x; i < NB; i += 256)
        hist_g[i * B_SORT + blockIdx.x] = hist[i];
}

// ------------------- K2a: per-bucket scan over blocks (in-place) + bin totals
__global__ __launch_bounds__(B_SORT) void scanbins_kernel(int* __restrict__ hist_g,
                                                          int* __restrict__ binTotal) {
    __shared__ int s[B_SORT];
    const int bin = blockIdx.x, t = threadIdx.x;
    int v = hist_g[bin * B_SORT + t];
    s[t] = v;
    __syncthreads();
#pragma unroll
    for (int off = 1; off < B_SORT; off <<= 1) {
        int u = (t >= off) ? s[t - off] : 0;
        __syncthreads();
        s[t] += u;
        __syncthreads();
    }
    hist_g[bin * B_SORT + t] = s[t] - v;          // exclusive within bin
    if (t == B_SORT - 1) binTotal[bin] = s[t];
}

// --------------------- K2b: scan bucket totals -> bucket starts (2/thread)
__global__ __launch_bounds__(1024) void scanoff_kernel(const int* __restrict__ binTotal,
                                                       int* __restrict__ binStart) {
    __shared__ int s[1024];
    const int t = threadIdx.x;
    const int i0 = 2 * t, i1 = 2 * t + 1;
    int v0 = (i0 < NB) ? binTotal[i0] : 0;
    int v1 = (i1 < NB) ? binTotal[i1] : 0;
    s[t] = v0 + v1;
    __syncthreads();
#pragma unroll
    for (int off = 1; off < 1024; off <<= 1) {
        int u = (t >= off) ? s[t - off] : 0;
        __syncthreads();
        s[t] += u;
        __syncthreads();
    }
    int base = s[t] - v0 - v1;                    // exclusive at i0
    if (i0 < NB) binStart[i0] = base;
    if (i1 < NB) binStart[i1] = base + v0;
    if (t == 0) binStart[NB] = N_EDGES;
}

// ---------- K3: bucket-partition packed edges (LDS cursors, no g-atomics)
__global__ __launch_bounds__(256) void scatter_kernel(const int* __restrict__ eidx,
                                                      const int* __restrict__ hist_g,
                                                      const int* __restrict__ binStart,
                                                      unsigned int* __restrict__ packs) {
    __shared__ int cur[NB];
    for (int i = threadIdx.x; i < NB; i += 256)
        cur[i] = binStart[i] + hist_g[i * B_SORT + blockIdx.x];
    __syncthreads();
    const int beg = blockIdx.x * EPB;
    for (int e = beg + threadIdx.x; e < beg + EPB; e += 256) {
        int row = eidx[e];
        int col = eidx[N_EDGES + e];
        int p = atomicAdd(&cur[col >> 6], 1);     // LDS atomic only
        packs[p] = ((unsigned)row << 6) | (unsigned)(col & 63);
    }
}

// ----------------------------- K4: per-bucket degree -> dis = rsqrt(deg+1)
__global__ __launch_bounds__(256) void degdis_kernel(const unsigned int* __restrict__ packs,
                                                     const int* __restrict__ binStart,
                                                     float* __restrict__ dis) {
    __shared__ int cnt[NPB];
    const int b = blockIdx.x, t = threadIdx.x;
    if (t < NPB) cnt[t] = 0;
    __syncthreads();
    const int beg = binStart[b], end = binStart[b + 1];
    for (int i = beg + t; i < end; i += 256)
        atomicAdd(&cnt[packs[i] & 63], 1);
    __syncthreads();
    const int n0 = b << 6;
    if (t < NPB && n0 + t < N_NODES)
        dis[n0 + t] = rsqrtf((float)cnt[t] + 1.0f);
}

// ------------------------------------------------- W [128][64] -> WT bf16 --
__global__ __launch_bounds__(256) void wt_kernel(const float* __restrict__ W,
                                                 unsigned short* __restrict__ WT) {
    int idx = blockIdx.x * 256 + threadIdx.x;
    if (idx < IN_F * OUT_F) {
        int k = idx >> 6, n = idx & 63;
        WT[n * IN_F + k] = f2b(W[idx]);
    }
}

// ------------------------------------- hb = bf16(dis * (x @ W)) ------------
// mfma_f32_16x16x32_bf16; LDS XOR-swizzled bf16 tiles (verified R5/R6).
// Pre-scaling by dis[row] removes the per-edge dis gather in K5.
constexpr int GEMM_ROWS = 64;
__global__ __launch_bounds__(256) void gemm_kernel(const float* __restrict__ x,
                                                   const unsigned short* __restrict__ WT,
                                                   const float* __restrict__ dis,
                                                   unsigned short* __restrict__ h) {
    __shared__ unsigned short Xs[GEMM_ROWS][IN_F];   // 16 KB
    __shared__ unsigned short Ws[OUT_F][IN_F];       // 16 KB (W^T: [n][k])
    const int tid = threadIdx.x;
    const int row0 = blockIdx.x * GEMM_ROWS;

#pragma unroll
    for (int j = 0; j < 4; ++j) {
        int g  = tid + j * 256;
        int n  = g >> 4;
        int k8 = (g & 15) * 8;
        bf16x8 v = *(const bf16x8*)&WT[n * IN_F + k8];
        *(bf16x8*)&Ws[n][k8 ^ ((n & 7) << 3)] = v;
    }
    {
        int r    = tid >> 2;
        int grow = row0 + r;
        if (grow >= N_NODES) grow = N_NODES - 1;
        int ks   = (tid & 3) * 32;
        const float4* xp = (const float4*)x + (long)grow * (IN_F / 4) + (ks >> 2);
        int sw = (r & 7) << 3;
#pragma unroll
        for (int j = 0; j < 8; ++j) {
            float4 xv = xp[j];
            unsigned int u0 = (unsigned int)f2b(xv.x) | ((unsigned int)f2b(xv.y) << 16);
            unsigned int u1 = (unsigned int)f2b(xv.z) | ((unsigned int)f2b(xv.w) << 16);
            uint2 pr; pr.x = u0; pr.y = u1;
            *(uint2*)&Xs[r][(ks + j * 4) ^ sw] = pr;
        }
    }
    __syncthreads();

    const int w    = tid >> 6;
    const int lane = tid & 63;
    const int ml   = lane & 15;
    const int kg   = lane >> 4;

    const int rowA = w * 16 + ml;
    const int swA  = (rowA & 7) << 3;

    bf16x8 a[4];
#pragma unroll
    for (int kt = 0; kt < 4; ++kt)
        a[kt] = *(const bf16x8*)&Xs[rowA][(kt * 32 + kg * 8) ^ swA];

    f32x4 acc[4];
#pragma unroll
    for (int ct = 0; ct < 4; ++ct) acc[ct] = (f32x4)(0.0f);

#pragma unroll
    for (int ct = 0; ct < 4; ++ct) {
        int n  = ct * 16 + ml;
        int sw = (n & 7) << 3;
#pragma unroll
        for (int kt = 0; kt < 4; ++kt) {
            bf16x8 bv = *(const bf16x8*)&Ws[n][(kt * 32 + kg * 8) ^ sw];
            acc[ct] = __builtin_amdgcn_mfma_f32_16x16x32_bf16(a[kt], bv, acc[ct], 0, 0, 0);
        }
    }

    const int grow0 = row0 + w * 16 + kg * 4;
#pragma unroll
    for (int i = 0; i < 4; ++i) {
        int r = grow0 + i;
        if (r < N_NODES) {
            float ds = dis[r];
#pragma unroll
            for (int ct = 0; ct < 4; ++ct)
                h[(long)r * OUT_F + ct * 16 + ml] = f2b(ds * acc[ct][i]);
        }
    }
}

// ---- K5: fused CSR-build + gather (REGISTER accumulation, R6 style) -------
// One block per bucket: stage packs in LDS, per-node count/scan/reorder in
// LDS (int atomics only), then 4 waves x 16 nodes each: half-wave per
// alternate edge, lane sl = bf16x2 feature pair, shfl_xor(32) combine.
// out = dc*(sum hb[row] + hb[node]) + b   (hb pre-scaled by dis).
__global__ __launch_bounds__(256) void gather_kernel(const unsigned int* __restrict__ packs,
                                                     const int* __restrict__ binStart,
                                                     const float* __restrict__ dis,
                                                     const unsigned int* __restrict__ h2,
                                                     const float* __restrict__ bias,
                                                     float* __restrict__ out) {
    __shared__ unsigned int stage[STAGE_CAP];
    __shared__ unsigned int sorted[STAGE_CAP];
    __shared__ int cnt[NPB], sx[NPB], curs[NPB];
    __shared__ float disL[NPB];
    const int b = blockIdx.x, t = threadIdx.x;
    const int beg = binStart[b], end = binStart[b + 1];
    const int size = end - beg;
    const int n0 = b << 6;

    if (t < NPB) {
        cnt[t] = 0;
        disL[t] = (n0 + t < N_NODES) ? dis[n0 + t] : 0.0f;
    }
    __syncthreads();

    const bool fits = (size <= STAGE_CAP);
    if (fits) {
        for (int i = t; i < size; i += 256) {
            unsigned int pk = packs[beg + i];
            stage[i] = pk;
            atomicAdd(&cnt[pk & 63], 1);
        }
        __syncthreads();
        if (t < NPB) sx[t] = cnt[t];
        __syncthreads();
#pragma unroll
        for (int off = 1; off < NPB; off <<= 1) {
            int u = (t < NPB && t >= off) ? sx[t - off] : 0;
            __syncthreads();
            if (t < NPB) sx[t] += u;
            __syncthreads();
        }
        if (t < NPB) curs[t] = sx[t] - cnt[t];    // exclusive start
        __syncthreads();
        for (int i = t; i < size; i += 256) {
            unsigned int pk = stage[i];
            int q = atomicAdd(&curs[pk & 63], 1);
            sorted[q] = pk;
        }
        __syncthreads();
    }

    const int lane = t & 63;
    const int half = lane >> 5;
    const int sl   = lane & 31;
    const int w    = t >> 6;

    for (int c = w; c < NPB; c += 4) {
        int node = n0 + c;
        if (node >= N_NODES) break;               // uniform per wave
        float ax = 0.0f, ay = 0.0f;
        if (fits) {
            int s1 = sx[c], s0 = s1 - cnt[c];
            for (int i = s0 + half; i < s1; i += 2) {
                int row = (int)(sorted[i] >> 6);  // uniform per half
                unsigned int u = h2[row * 32 + sl];
                ax += blo(u); ay += bhi(u);
            }
        } else {
            // overflow fallback (prob ~0): stream bucket from global, filter
            for (int i = beg + half; i < end; i += 2) {
                unsigned int pk = packs[i];
                if ((int)(pk & 63) == c) {
                    int row = (int)(pk >> 6);
                    unsigned int u = h2[row * 32 + sl];
                    ax += blo(u); ay += bhi(u);
                }
            }
        }
        ax += __shfl_xor(ax, 32);
        ay += __shfl_xor(ay, 32);

        if (half == 0) {
            float dc = disL[c];
            unsigned int us = h2[node * 32 + sl]; // hb[node] = dis*h
            float2 bv = ((const float2*)bias)[sl];
            float2 o;
            o.x = dc * (ax + blo(us)) + bv.x;
            o.y = dc * (ay + bhi(us)) + bv.y;
            ((float2*)out)[node * 32 + sl] = o;
        }
    }
}

// ---------------------------------------------------------------------------
extern "C" void kernel_launch(void* const* d_in, const int* in_sizes, int n_in,
                              void* d_out, int out_size, void* d_ws, size_t ws_size,
                              hipStream_t stream) {
    const float* x   = (const float*)d_in[0];
    const int*   idx = (const int*)d_in[1];   // [2, E], delivered as int32
    const float* W   = (const float*)d_in[2];
    const float* b   = (const float*)d_in[3];
    float*       out = (float*)d_out;

    int* p = (int*)d_ws;
    unsigned int* packs = (unsigned int*)p;  p += N_EDGES;       // 6.4 MB
    int* hist_g   = p;                       p += NB * B_SORT;   // 1.6 MB
    int* binTotal = p;                       p += NB + 4;
    int* binStart = p;                       p += NB + 4;
    float* dis    = (float*)p;               p += N_NODES;
    p = (int*)(((uintptr_t)p + 15) & ~(uintptr_t)15);            // 16B align
    unsigned short* WT = (unsigned short*)p; p += IN_F * OUT_F / 2;
    unsigned short* hb = (unsigned short*)p;                     // 12.8 MB

    hist_kernel<<<B_SORT, 256, 0, stream>>>(idx + N_EDGES, hist_g);
    scanbins_kernel<<<NB, B_SORT, 0, stream>>>(hist_g, binTotal);
    scanoff_kernel<<<1, 1024, 0, stream>>>(binTotal, binStart);
    scatter_kernel<<<B_SORT, 256, 0, stream>>>(idx, hist_g, binStart, packs);
    degdis_kernel<<<NB, 256, 0, stream>>>(packs, binStart, dis);
    wt_kernel<<<(IN_F * OUT_F + 255) / 256, 256, 0, stream>>>(W, WT);
    gemm_kernel<<<(N_NODES + GEMM_ROWS - 1) / GEMM_ROWS, 256, 0, stream>>>(x, WT, dis, hb);
    gather_kernel<<<NB, 256, 0, stream>>>(packs, binStart, dis,
                                          (const unsigned int*)hb, b, out);
}